// Round 17
// baseline (401.096 us; speedup 1.0000x reference)
//
#include <hip/hip_runtime.h>

#define TPK 512    // K0 (wft + fills) block size
#define TPA 1024   // K2 (active) block size
#define REP 5      // DIAGNOSTIC: in-kernel repetition so our dispatches exceed
                   // the ~155us harness poison-fills and surface in top-5
                   // rocprof rows with their counters. Idempotent.

typedef float f4v __attribute__((ext_vector_type(4)));

// bit-reverse 7 bits
__device__ __forceinline__ int br7(int k) {
  return (int)(__brev((unsigned int)k) >> 25);
}

template <int NT>
__device__ __forceinline__ void zero_fill_slab(float* __restrict__ out,
                                               int zi, int tid) {
  const int zb = zi / 224;
  const int zh = 16 + (zi - zb * 224);
  f4v* o4 = (f4v*)(out + ((size_t)(zb * 256 + zh)) * 32768);
  const f4v z = {0.f, 0.f, 0.f, 0.f};
  #pragma unroll 4
  for (int i = tid; i < 8192; i += NT)
    __builtin_nontemporal_store(z, &o4[i]);
}

// 16-point in-register radix-2 DIT FFT, sign +. Input bit-reversed, output natural.
__device__ __forceinline__ void fft16_pos(float* ar, float* ai) {
  constexpr float TC[4][8] = {
    {1.f, 0.f, 0.f, 0.f, 0.f, 0.f, 0.f, 0.f},
    {1.f, 0.f, 0.f, 0.f, 0.f, 0.f, 0.f, 0.f},
    {1.f, 0.70710678f, 0.f, -0.70710678f, 0.f, 0.f, 0.f, 0.f},
    {1.f, 0.92387953f, 0.70710678f, 0.38268343f, 0.f, -0.38268343f, -0.70710678f, -0.92387953f}
  };
  constexpr float TS[4][8] = {
    {0.f, 0.f, 0.f, 0.f, 0.f, 0.f, 0.f, 0.f},
    {0.f, 1.f, 0.f, 0.f, 0.f, 0.f, 0.f, 0.f},
    {0.f, 0.70710678f, 1.f, 0.70710678f, 0.f, 0.f, 0.f, 0.f},
    {0.f, 0.38268343f, 0.70710678f, 0.92387953f, 1.f, 0.92387953f, 0.70710678f, 0.38268343f}
  };
  #pragma unroll
  for (int s = 0; s < 4; ++s) {
    const int L = 1 << s;
    #pragma unroll
    for (int jj = 0; jj < 8; ++jj) {
      if (jj < L) {
        const float tc = TC[s][jj], ts = TS[s][jj];
        #pragma unroll
        for (int i0 = jj; i0 < 16; i0 += 2 * L) {
          const float xr = ar[i0 + L], xi = ai[i0 + L];
          const float pr = xr * tc - xi * ts;
          const float pi = xr * ts + xi * tc;
          const float qr = ar[i0], qi = ai[i0];
          ar[i0 + L] = qr - pr; ai[i0 + L] = qi - pi;
          ar[i0]     = qr + pr; ai[i0]     = qi + pi;
        }
      }
    }
  }
}

// Phase A: W-direction partial DFT + cross-group reduction.
template <int TPBv>
__device__ void phaseA_reduce(const float* __restrict__ src,
                              float (*XR)[128], float (*XI)[128],
                              float (*SR)[128], float (*SI)[128],
                              const float* Rc, const float* Rs, int tid) {
  constexpr int NQ = TPBv / 128;
  constexpr int JN = 16 / NQ;
  const int c = tid & 127;
  const int q = tid >> 7;

  constexpr float C16[16] = {1.f, 0.92387953f, 0.70710678f, 0.38268343f, 0.f,
                             -0.38268343f, -0.70710678f, -0.92387953f, -1.f,
                             -0.92387953f, -0.70710678f, -0.38268343f, 0.f,
                             0.38268343f, 0.70710678f, 0.92387953f};
  constexpr float S16[16] = {0.f, 0.38268343f, 0.70710678f, 0.92387953f, 1.f,
                             0.92387953f, 0.70710678f, 0.38268343f, 0.f,
                             -0.38268343f, -0.70710678f, -0.92387953f, -1.f,
                             -0.92387953f, -0.70710678f, -0.38268343f};

  float accR[17], accI[17];
  #pragma unroll
  for (int f = 0; f < 17; ++f) { accR[f] = 0.f; accI[f] = 0.f; }

  #pragma unroll
  for (int j = 0; j < JN; ++j) {
    const int w0 = q * JN + j;
    float xv[16];
    #pragma unroll
    for (int w1 = 0; w1 < 16; ++w1)
      xv[w1] = src[(w1 * 16 + w0) * 128 + c];
    float SRe[9], SIm[9];
    #pragma unroll
    for (int g = 0; g < 9; ++g) {
      float sr = 0.f, si = 0.f;
      #pragma unroll
      for (int w1 = 0; w1 < 16; ++w1) {
        const int m = (g * w1) & 15;
        sr = fmaf(xv[w1], C16[m], sr);
        si = fmaf(xv[w1], -S16[m], si);
      }
      SRe[g] = sr; SIm[g] = si;
    }
    #pragma unroll
    for (int f = 0; f < 17; ++f) {
      const int g = f & 15;
      const float sr = (g <= 8) ? SRe[g] : SRe[16 - g];
      const float si = (g <= 8) ? SIm[g] : -SIm[16 - g];
      const int idx = (f * w0) & 255;
      const float tc = Rc[idx], ts = -Rs[idx];
      accR[f] = fmaf(sr, tc, fmaf(-si, ts, accR[f]));
      accI[f] = fmaf(sr, ts, fmaf(si, tc, accI[f]));
    }
  }
  #pragma unroll
  for (int r = 0; r < NQ / 2; ++r) {
    if (q == 2 * r) {
      if (r == 0) {
        #pragma unroll
        for (int f = 0; f < 17; ++f) { XR[f][c] = accR[f]; XI[f][c] = accI[f]; }
      } else {
        #pragma unroll
        for (int f = 0; f < 17; ++f) { XR[f][c] += accR[f]; XI[f][c] += accI[f]; }
      }
    } else if (q == 2 * r + 1) {
      if (r == 0) {
        #pragma unroll
        for (int f = 0; f < 17; ++f) { SR[f][c] = accR[f]; SI[f][c] = accI[f]; }
      } else {
        #pragma unroll
        for (int f = 0; f < 17; ++f) { SR[f][c] += accR[f]; SI[f][c] += accI[f]; }
      }
    }
    __syncthreads();
  }
  for (int u = tid; u < 17 * 128; u += TPBv) {
    const int row = u >> 7, cc = u & 127;
    XR[row][cc] += SR[row][cc];
    XI[row][cc] += SI[row][cc];
  }
  __syncthreads();
}

// 128-pt LDS DIF FFT (sign -, natural -> bit-reversed), 17 rows (K0 path).
template <int TPBv>
__device__ void fftc17_lds(float (*XR)[128], float (*XI)[128],
                           const float* Rc, const float* Rs, int tid) {
  for (int s = 6; s >= 0; --s) {
    const int L = 1 << s;
    for (int u = tid; u < 17 * 64; u += TPBv) {
      const int row = u >> 6, qq = u & 63;
      const int jj = qq & (L - 1);
      const int pos = ((qq >> s) << (s + 1)) | jj;
      const int ti = jj << (7 - s);
      const float tc = Rc[ti], ts = Rs[ti];
      const float a0r = XR[row][pos],     a0i = XI[row][pos];
      const float b0r = XR[row][pos + L], b0i = XI[row][pos + L];
      XR[row][pos] = a0r + b0r; XI[row][pos] = a0i + b0i;
      const float dr = a0r - b0r, di = a0i - b0i;
      XR[row][pos + L] = fmaf(dr, tc, di * ts);
      XI[row][pos + L] = fmaf(di, tc, -dr * ts);
    }
    __syncthreads();
  }
}

// K0: blocks 0..63 precompute w_ft/b_ft (x REP); blocks 64.. zero-fill all
// 1792 inactive output slabs (x REP).
__global__ __launch_bounds__(TPK) void k0_wft_and_fill(
    const float* __restrict__ wp, const float* __restrict__ bp,
    float2* __restrict__ wsW, float2* __restrict__ wsB,
    float* __restrict__ out) {
  const int bid = blockIdx.x;
  const int tid = threadIdx.x;
  if (bid >= 64) {
    for (int rep = 0; rep < REP; ++rep)
      zero_fill_slab<TPK>(out, bid - 64, tid);
    return;
  }
  __shared__ float XR[17][128], XI[17][128];
  __shared__ float SR[17][128], SI[17][128];
  __shared__ float Rc[256], Rs[256];
  for (int i = tid; i < 256; i += TPK) {
    float sv, cv; sincosf(6.283185307179586f * (float)i / 256.0f, &sv, &cv);
    Rc[i] = cv; Rs[i] = sv;
  }
  __syncthreads();
  const int which = bid >> 5;   // 0 = w, 1 = b
  const int ha = bid & 31;
  const int h = (ha < 16) ? ha : (224 + ha);
  const float* src = (which ? bp : wp) + (size_t)h * 32768;
  for (int rep = 0; rep < REP; ++rep) {
    phaseA_reduce<TPK>(src, XR, XI, SR, SI, Rc, Rs, tid);
    fftc17_lds<TPK>(XR, XI, Rc, Rs, tid);
    float2* dst = which ? wsB : wsW;
    for (int u = tid; u < 32 * 65; u += TPK) {
      const int fi = u / 65, k = u - fi * 65;
      const int f = fi - 16;
      float xr, xi;
      if (f >= 0) { const int p = br7(k); xr = XR[f][p]; xi = XI[f][p]; }
      else { const int kk = (128 - k) & 127; const int p = br7(kk);
             xr = XR[-f][p]; xi = -XI[-f][p]; }
      dst[(ha * 32 + fi) * 65 + k] = make_float2(xr, xi);
    }
    __syncthreads();
  }
}

// K2: 256 active slabs, 1024 thr. Register shfl-FFT version (R11). x REP.
__global__ __launch_bounds__(TPA) void fourier_active(
    const float* __restrict__ x, const float2* __restrict__ wsW,
    const float2* __restrict__ wsB, float* __restrict__ out) {
  const int bid = blockIdx.x;
  const int tid = threadIdx.x;
  __shared__ float XR[17][128], XI[17][128];
  __shared__ float TR[32][128], TI[32][128];
  __shared__ float Rc[256], Rs[256];
  for (int i = tid; i < 256; i += TPA) {
    float sv, cv; sincosf(6.283185307179586f * (float)i / 256.0f, &sv, &cv);
    Rc[i] = cv; Rs[i] = sv;
  }
  __syncthreads();

  const int b = bid >> 5;
  const int ha = bid & 31;
  const int h = (ha < 16) ? ha : (224 + ha);
  const float* src = x + ((size_t)(b * 256 + h)) * 32768;

  for (int rep = 0; rep < REP; ++rep) {
  phaseA_reduce<TPA>(src, XR, XI, (float(*)[128])TR, (float(*)[128])TI,
                     Rc, Rs, tid);

  const int wid = tid >> 6, lane = tid & 63;
  const int i0 = lane, i1 = lane + 64;

  // Forward 128-pt DIF (sign -) in registers.
  for (int row = wid; row < 17; row += 16) {
    float ar0 = XR[row][i0], ai0 = XI[row][i0];
    float ar1 = XR[row][i1], ai1 = XI[row][i1];
    {
      const float tc = Rc[2 * lane], ts = Rs[2 * lane];
      const float sr = ar0 - ar1, si = ai0 - ai1;
      ar0 += ar1; ai0 += ai1;
      ar1 = fmaf(sr, tc,  si * ts);
      ai1 = fmaf(si, tc, -sr * ts);
    }
    #pragma unroll
    for (int s = 5; s >= 0; --s) {
      const int L = 1 << s;
      const int m2 = (lane & (L - 1)) << (7 - s);
      const float wc = Rc[m2], wsn = Rs[m2];
      const bool hi = (lane & L) != 0;
      const float br0 = __shfl_xor(ar0, L), bi0 = __shfl_xor(ai0, L);
      const float br1 = __shfl_xor(ar1, L), bi1 = __shfl_xor(ai1, L);
      float dr0 = hi ? (br0 - ar0) : (ar0 + br0);
      float di0 = hi ? (bi0 - ai0) : (ai0 + bi0);
      float dr1 = hi ? (br1 - ar1) : (ar1 + br1);
      float di1 = hi ? (bi1 - ai1) : (ai1 + bi1);
      if (hi) {
        const float t0 = fmaf(dr0, wc,  di0 * wsn);
        di0 = fmaf(di0, wc, -dr0 * wsn); dr0 = t0;
        const float t1 = fmaf(dr1, wc,  di1 * wsn);
        di1 = fmaf(di1, wc, -dr1 * wsn); dr1 = t1;
      }
      ar0 = dr0; ai0 = di0; ar1 = dr1; ai1 = di1;
    }
    XR[row][i0] = ar0; XI[row][i0] = ai0;
    XR[row][i1] = ar1; XI[row][i1] = ai1;
  }
  __syncthreads();

  // Pointwise + inverse 128-pt DIT (sign +) in registers, 2 rows per wave.
  const int k0 = br7(i0);
  const int k1 = k0 + 1;
  #pragma unroll
  for (int rr = 0; rr < 2; ++rr) {
    int fi; float xr0, xi0, xr1, xi1;
    if (rr == 0) {
      fi = wid + 16;
      xr0 = XR[wid][i0]; xi0 = XI[wid][i0];
      xr1 = XR[wid][i1]; xi1 = XI[wid][i1];
    } else {
      fi = wid;
      const int mrow = 16 - wid;
      const int pm0 = br7((128 - k0) & 127);
      const int pm1 = br7((128 - k1) & 127);
      xr0 = XR[mrow][pm0]; xi0 = -XI[mrow][pm0];
      xr1 = XR[mrow][pm1]; xi1 = -XI[mrow][pm1];
    }
    float gr0 = 0.f, gi0 = 0.f, gr1 = 0.f, gi1 = 0.f;
    const float2* wrow = &wsW[(ha * 32 + fi) * 65];
    const float2* brow = &wsB[(ha * 32 + fi) * 65];
    if (k0 <= 64) {
      const float2 wf = wrow[k0], bf = brow[k0];
      const float al = (k0 == 0 || k0 == 64) ? 1.f : 2.f;
      gr0 = al * (xr0 * wf.x - xi0 * wf.y + bf.x);
      gi0 = al * (xr0 * wf.y + xi0 * wf.x + bf.y);
    }
    if (k1 <= 64) {
      const float2 wf = wrow[k1], bf = brow[k1];
      gr1 = 2.f * (xr1 * wf.x - xi1 * wf.y + bf.x);
      gi1 = 2.f * (xr1 * wf.y + xi1 * wf.x + bf.y);
    }
    #pragma unroll
    for (int s = 0; s <= 5; ++s) {
      const int L = 1 << s;
      const int m2 = (lane & (L - 1)) << (7 - s);
      const float wc = Rc[m2], wsn = Rs[m2];
      const bool hi = (lane & L) != 0;
      const float br0 = __shfl_xor(gr0, L), bi0 = __shfl_xor(gi0, L);
      const float br1 = __shfl_xor(gr1, L), bi1 = __shfl_xor(gi1, L);
      const float q0ri = hi ? gr0 : br0, q0ii = hi ? gi0 : bi0;
      const float q1ri = hi ? gr1 : br1, q1ii = hi ? gi1 : bi1;
      const float q0r = fmaf(q0ri, wc, -q0ii * wsn);
      const float q0i = fmaf(q0ii, wc,  q0ri * wsn);
      const float q1r = fmaf(q1ri, wc, -q1ii * wsn);
      const float q1i = fmaf(q1ii, wc,  q1ri * wsn);
      const float p0r = hi ? br0 : gr0, p0i = hi ? bi0 : gi0;
      const float p1r = hi ? br1 : gr1, p1i = hi ? bi1 : gi1;
      gr0 = hi ? (p0r - q0r) : (p0r + q0r);
      gi0 = hi ? (p0i - q0i) : (p0i + q0i);
      gr1 = hi ? (p1r - q1r) : (p1r + q1r);
      gi1 = hi ? (p1i - q1i) : (p1i + q1i);
    }
    {
      const float wc = Rc[2 * lane], wsn = Rs[2 * lane];
      const float qr = fmaf(gr1, wc, -gi1 * wsn);
      const float qi = fmaf(gi1, wc,  gr1 * wsn);
      gr1 = gr0 - qr; gi1 = gi0 - qi;
      gr0 = gr0 + qr; gi0 = gi0 + qi;
    }
    TR[fi][i0] = gr0; TI[fi][i0] = gi0;
    TR[fi][i1] = gr1; TI[fi][i1] = gi1;
  }
  __syncthreads();

  // phase E
  const int c = tid & 127;
  const int q = tid >> 7;
  constexpr int BR4[16] = {0, 8, 4, 12, 2, 10, 6, 14, 1, 9, 5, 13, 3, 11, 7, 15};
  const float inv = 1.0f / 32768.0f;
  float* og = out + ((size_t)(b * 256 + h)) * 32768;

  #pragma unroll 1
  for (int it = 0; it < 2; ++it) {
    const int w0 = q + it * 8;
    float Ur[16], Ui[16];
    #pragma unroll
    for (int g = 0; g < 16; ++g) {
      const int gb = BR4[g];
      const float t1r = TR[gb + 16][c], t1i = TI[gb + 16][c];
      const float t0r = TR[gb][c],      t0i = TI[gb][c];
      const int iw1 = (gb * w0) & 255;
      const int iw2 = ((gb - 16) * w0) & 255;
      const float c1 = Rc[iw1], s1 = Rs[iw1];
      const float c2 = Rc[iw2], s2 = Rs[iw2];
      Ur[g] = t1r * c1 - t1i * s1 + t0r * c2 - t0i * s2;
      Ui[g] = t1r * s1 + t1i * c1 + t0r * s2 + t0i * c2;
    }
    fft16_pos(Ur, Ui);
    #pragma unroll
    for (int w1 = 0; w1 < 16; ++w1)
      og[(w1 * 16 + w0) * 128 + c] = Ur[w1] * inv;
  }
  __syncthreads();
  } // rep
}

extern "C" void kernel_launch(void* const* d_in, const int* in_sizes, int n_in,
                              void* d_out, int out_size, void* d_ws, size_t ws_size,
                              hipStream_t stream) {
  const float* x = (const float*)d_in[0];
  const float* w = (const float*)d_in[1];
  const float* b = (const float*)d_in[2];
  float* out = (float*)d_out;
  float2* wsW = (float2*)d_ws;
  float2* wsB = wsW + 32 * 32 * 65;   // 66560 float2 each (532,480 B)

  hipLaunchKernelGGL(k0_wft_and_fill, dim3(64 + 1792), dim3(TPK), 0, stream,
                     w, b, wsW, wsB, out);
  hipLaunchKernelGGL(fourier_active, dim3(256), dim3(TPA), 0, stream,
                     x, wsW, wsB, out);
}

// Round 18
// 78.445 us; speedup vs baseline: 5.1131x; 5.1131x over previous
//
#include <hip/hip_runtime.h>

#define TPK 512    // K0 (wft + fills) block size
#define TPA 1024   // K2 (active + fills) block size
#define NF0 256    // fill slabs in K0 (1792 - 1536)
#define NF2 1536   // fill slabs co-resident in K2

typedef float f4v __attribute__((ext_vector_type(4)));

// bit-reverse 7 bits
__device__ __forceinline__ int br7(int k) {
  return (int)(__brev((unsigned int)k) >> 25);
}

template <int NT>
__device__ __forceinline__ void zero_fill_slab(float* __restrict__ out,
                                               int zi, int tid) {
  const int zb = zi / 224;
  const int zh = 16 + (zi - zb * 224);
  f4v* o4 = (f4v*)(out + ((size_t)(zb * 256 + zh)) * 32768);
  const f4v z = {0.f, 0.f, 0.f, 0.f};
  #pragma unroll
  for (int i = 0; i < 8192 / NT; ++i)
    __builtin_nontemporal_store(z, &o4[tid + i * NT]);
}

// 16-point in-register radix-2 DIT FFT, sign +. Input bit-reversed, output natural.
__device__ __forceinline__ void fft16_pos(float* ar, float* ai) {
  constexpr float TC[4][8] = {
    {1.f, 0.f, 0.f, 0.f, 0.f, 0.f, 0.f, 0.f},
    {1.f, 0.f, 0.f, 0.f, 0.f, 0.f, 0.f, 0.f},
    {1.f, 0.70710678f, 0.f, -0.70710678f, 0.f, 0.f, 0.f, 0.f},
    {1.f, 0.92387953f, 0.70710678f, 0.38268343f, 0.f, -0.38268343f, -0.70710678f, -0.92387953f}
  };
  constexpr float TS[4][8] = {
    {0.f, 0.f, 0.f, 0.f, 0.f, 0.f, 0.f, 0.f},
    {0.f, 1.f, 0.f, 0.f, 0.f, 0.f, 0.f, 0.f},
    {0.f, 0.70710678f, 1.f, 0.70710678f, 0.f, 0.f, 0.f, 0.f},
    {0.f, 0.38268343f, 0.70710678f, 0.92387953f, 1.f, 0.92387953f, 0.70710678f, 0.38268343f}
  };
  #pragma unroll
  for (int s = 0; s < 4; ++s) {
    const int L = 1 << s;
    #pragma unroll
    for (int jj = 0; jj < 8; ++jj) {
      if (jj < L) {
        const float tc = TC[s][jj], ts = TS[s][jj];
        #pragma unroll
        for (int i0 = jj; i0 < 16; i0 += 2 * L) {
          const float xr = ar[i0 + L], xi = ai[i0 + L];
          const float pr = xr * tc - xi * ts;
          const float pi = xr * ts + xi * tc;
          const float qr = ar[i0], qi = ai[i0];
          ar[i0 + L] = qr - pr; ai[i0 + L] = qi - pi;
          ar[i0]     = qr + pr; ai[i0]     = qi + pi;
        }
      }
    }
  }
}

// Phase A: W-direction partial DFT + cross-group reduction.
template <int TPBv>
__device__ void phaseA_reduce(const float* __restrict__ src,
                              float (*XR)[128], float (*XI)[128],
                              float (*SR)[128], float (*SI)[128],
                              const float* Rc, const float* Rs, int tid) {
  constexpr int NQ = TPBv / 128;
  constexpr int JN = 16 / NQ;
  const int c = tid & 127;
  const int q = tid >> 7;

  constexpr float C16[16] = {1.f, 0.92387953f, 0.70710678f, 0.38268343f, 0.f,
                             -0.38268343f, -0.70710678f, -0.92387953f, -1.f,
                             -0.92387953f, -0.70710678f, -0.38268343f, 0.f,
                             0.38268343f, 0.70710678f, 0.92387953f};
  constexpr float S16[16] = {0.f, 0.38268343f, 0.70710678f, 0.92387953f, 1.f,
                             0.92387953f, 0.70710678f, 0.38268343f, 0.f,
                             -0.38268343f, -0.70710678f, -0.92387953f, -1.f,
                             -0.92387953f, -0.70710678f, -0.38268343f};

  float accR[17], accI[17];
  #pragma unroll
  for (int f = 0; f < 17; ++f) { accR[f] = 0.f; accI[f] = 0.f; }

  #pragma unroll
  for (int j = 0; j < JN; ++j) {
    const int w0 = q * JN + j;
    float xv[16];
    #pragma unroll
    for (int w1 = 0; w1 < 16; ++w1)
      xv[w1] = src[(w1 * 16 + w0) * 128 + c];
    float SRe[9], SIm[9];
    #pragma unroll
    for (int g = 0; g < 9; ++g) {
      float sr = 0.f, si = 0.f;
      #pragma unroll
      for (int w1 = 0; w1 < 16; ++w1) {
        const int m = (g * w1) & 15;
        sr = fmaf(xv[w1], C16[m], sr);
        si = fmaf(xv[w1], -S16[m], si);
      }
      SRe[g] = sr; SIm[g] = si;
    }
    #pragma unroll
    for (int f = 0; f < 17; ++f) {
      const int g = f & 15;
      const float sr = (g <= 8) ? SRe[g] : SRe[16 - g];
      const float si = (g <= 8) ? SIm[g] : -SIm[16 - g];
      const int idx = (f * w0) & 255;
      const float tc = Rc[idx], ts = -Rs[idx];
      accR[f] = fmaf(sr, tc, fmaf(-si, ts, accR[f]));
      accI[f] = fmaf(sr, ts, fmaf(si, tc, accI[f]));
    }
  }
  #pragma unroll
  for (int r = 0; r < NQ / 2; ++r) {
    if (q == 2 * r) {
      if (r == 0) {
        #pragma unroll
        for (int f = 0; f < 17; ++f) { XR[f][c] = accR[f]; XI[f][c] = accI[f]; }
      } else {
        #pragma unroll
        for (int f = 0; f < 17; ++f) { XR[f][c] += accR[f]; XI[f][c] += accI[f]; }
      }
    } else if (q == 2 * r + 1) {
      if (r == 0) {
        #pragma unroll
        for (int f = 0; f < 17; ++f) { SR[f][c] = accR[f]; SI[f][c] = accI[f]; }
      } else {
        #pragma unroll
        for (int f = 0; f < 17; ++f) { SR[f][c] += accR[f]; SI[f][c] += accI[f]; }
      }
    }
    __syncthreads();
  }
  for (int u = tid; u < 17 * 128; u += TPBv) {
    const int row = u >> 7, cc = u & 127;
    XR[row][cc] += SR[row][cc];
    XI[row][cc] += SI[row][cc];
  }
  __syncthreads();
}

// 128-pt LDS DIF FFT (sign -, natural -> bit-reversed), 17 rows (K0 path).
template <int TPBv>
__device__ void fftc17_lds(float (*XR)[128], float (*XI)[128],
                           const float* Rc, const float* Rs, int tid) {
  for (int s = 6; s >= 0; --s) {
    const int L = 1 << s;
    for (int u = tid; u < 17 * 64; u += TPBv) {
      const int row = u >> 6, qq = u & 63;
      const int jj = qq & (L - 1);
      const int pos = ((qq >> s) << (s + 1)) | jj;
      const int ti = jj << (7 - s);
      const float tc = Rc[ti], ts = Rs[ti];
      const float a0r = XR[row][pos],     a0i = XI[row][pos];
      const float b0r = XR[row][pos + L], b0i = XI[row][pos + L];
      XR[row][pos] = a0r + b0r; XI[row][pos] = a0i + b0i;
      const float dr = a0r - b0r, di = a0i - b0i;
      XR[row][pos + L] = fmaf(dr, tc, di * ts);
      XI[row][pos + L] = fmaf(di, tc, -dr * ts);
    }
    __syncthreads();
  }
}

// K0: blocks 0..63 precompute w_ft/b_ft; blocks 64.. fill first NF0 slabs
// (uses the 192 otherwise-idle CUs under the wft latency chain).
__global__ __launch_bounds__(TPK) void k0_wft_and_fill(
    const float* __restrict__ wp, const float* __restrict__ bp,
    float2* __restrict__ wsW, float2* __restrict__ wsB,
    float* __restrict__ out) {
  const int bid = blockIdx.x;
  const int tid = threadIdx.x;
  if (bid >= 64) {
    zero_fill_slab<TPK>(out, bid - 64, tid);
    return;
  }
  __shared__ float XR[17][128], XI[17][128];
  __shared__ float SR[17][128], SI[17][128];
  __shared__ float Rc[256], Rs[256];
  for (int i = tid; i < 256; i += TPK) {
    float sv, cv; sincosf(6.283185307179586f * (float)i / 256.0f, &sv, &cv);
    Rc[i] = cv; Rs[i] = sv;
  }
  __syncthreads();
  const int which = bid >> 5;   // 0 = w, 1 = b
  const int ha = bid & 31;
  const int h = (ha < 16) ? ha : (224 + ha);
  const float* src = (which ? bp : wp) + (size_t)h * 32768;
  phaseA_reduce<TPK>(src, XR, XI, SR, SI, Rc, Rs, tid);
  fftc17_lds<TPK>(XR, XI, Rc, Rs, tid);
  float2* dst = which ? wsB : wsW;
  for (int u = tid; u < 32 * 65; u += TPK) {
    const int fi = u / 65, k = u - fi * 65;
    const int f = fi - 16;
    float xr, xi;
    if (f >= 0) { const int p = br7(k); xr = XR[f][p]; xi = XI[f][p]; }
    else { const int kk = (128 - k) & 127; const int p = br7(kk);
           xr = XR[-f][p]; xi = -XI[-f][p]; }
    dst[(ha * 32 + fi) * 65 + k] = make_float2(xr, xi);
  }
}

// K2: blocks 0..255 = active slab pipeline (VGPR=64, LDS=52KB, 16 waves —
// measured R17); blocks 256..1791 = fill slabs. Counter-backed co-residency:
// 2 blocks/CU fit exactly (8 waves/SIMD x 64 VGPR = 512; 2x52KB <= 160KB LDS),
// and dispatch order places actives 1/CU first, so each CU runs 1 active +
// 1 fill block: fill waves stream NT stores through the idle 16 wave slots
// while the active latency chain runs.
__global__ __launch_bounds__(TPA) void fourier_active(
    const float* __restrict__ x, const float2* __restrict__ wsW,
    const float2* __restrict__ wsB, float* __restrict__ out) {
  const int bid = blockIdx.x;
  const int tid = threadIdx.x;
  if (bid >= 256) {
    zero_fill_slab<TPA>(out, NF0 + (bid - 256), tid);
    return;
  }
  __shared__ float XR[17][128], XI[17][128];
  __shared__ float TR[32][128], TI[32][128];
  __shared__ float Rc[256], Rs[256];
  for (int i = tid; i < 256; i += TPA) {
    float sv, cv; sincosf(6.283185307179586f * (float)i / 256.0f, &sv, &cv);
    Rc[i] = cv; Rs[i] = sv;
  }
  __syncthreads();

  const int b = bid >> 5;
  const int ha = bid & 31;
  const int h = (ha < 16) ? ha : (224 + ha);
  const float* src = x + ((size_t)(b * 256 + h)) * 32768;
  phaseA_reduce<TPA>(src, XR, XI, (float(*)[128])TR, (float(*)[128])TI,
                     Rc, Rs, tid);

  const int wid = tid >> 6, lane = tid & 63;
  const int i0 = lane, i1 = lane + 64;

  // Forward 128-pt DIF (sign -) in registers (R11-verified).
  for (int row = wid; row < 17; row += 16) {
    float ar0 = XR[row][i0], ai0 = XI[row][i0];
    float ar1 = XR[row][i1], ai1 = XI[row][i1];
    {
      const float tc = Rc[2 * lane], ts = Rs[2 * lane];
      const float sr = ar0 - ar1, si = ai0 - ai1;
      ar0 += ar1; ai0 += ai1;
      ar1 = fmaf(sr, tc,  si * ts);
      ai1 = fmaf(si, tc, -sr * ts);
    }
    #pragma unroll
    for (int s = 5; s >= 0; --s) {
      const int L = 1 << s;
      const int m2 = (lane & (L - 1)) << (7 - s);
      const float wc = Rc[m2], wsn = Rs[m2];
      const bool hi = (lane & L) != 0;
      const float br0 = __shfl_xor(ar0, L), bi0 = __shfl_xor(ai0, L);
      const float br1 = __shfl_xor(ar1, L), bi1 = __shfl_xor(ai1, L);
      float dr0 = hi ? (br0 - ar0) : (ar0 + br0);
      float di0 = hi ? (bi0 - ai0) : (ai0 + bi0);
      float dr1 = hi ? (br1 - ar1) : (ar1 + br1);
      float di1 = hi ? (bi1 - ai1) : (ai1 + bi1);
      if (hi) {
        const float t0 = fmaf(dr0, wc,  di0 * wsn);
        di0 = fmaf(di0, wc, -dr0 * wsn); dr0 = t0;
        const float t1 = fmaf(dr1, wc,  di1 * wsn);
        di1 = fmaf(di1, wc, -dr1 * wsn); dr1 = t1;
      }
      ar0 = dr0; ai0 = di0; ar1 = dr1; ai1 = di1;
    }
    XR[row][i0] = ar0; XI[row][i0] = ai0;
    XR[row][i1] = ar1; XI[row][i1] = ai1;
  }
  __syncthreads();

  // Pointwise + inverse 128-pt DIT (sign +) in registers, 2 rows per wave.
  const int k0 = br7(i0);
  const int k1 = k0 + 1;
  #pragma unroll
  for (int rr = 0; rr < 2; ++rr) {
    int fi; float xr0, xi0, xr1, xi1;
    if (rr == 0) {
      fi = wid + 16;
      xr0 = XR[wid][i0]; xi0 = XI[wid][i0];
      xr1 = XR[wid][i1]; xi1 = XI[wid][i1];
    } else {
      fi = wid;
      const int mrow = 16 - wid;
      const int pm0 = br7((128 - k0) & 127);
      const int pm1 = br7((128 - k1) & 127);
      xr0 = XR[mrow][pm0]; xi0 = -XI[mrow][pm0];
      xr1 = XR[mrow][pm1]; xi1 = -XI[mrow][pm1];
    }
    float gr0 = 0.f, gi0 = 0.f, gr1 = 0.f, gi1 = 0.f;
    const float2* wrow = &wsW[(ha * 32 + fi) * 65];
    const float2* brow = &wsB[(ha * 32 + fi) * 65];
    if (k0 <= 64) {
      const float2 wf = wrow[k0], bf = brow[k0];
      const float al = (k0 == 0 || k0 == 64) ? 1.f : 2.f;
      gr0 = al * (xr0 * wf.x - xi0 * wf.y + bf.x);
      gi0 = al * (xr0 * wf.y + xi0 * wf.x + bf.y);
    }
    if (k1 <= 64) {
      const float2 wf = wrow[k1], bf = brow[k1];
      gr1 = 2.f * (xr1 * wf.x - xi1 * wf.y + bf.x);
      gi1 = 2.f * (xr1 * wf.y + xi1 * wf.x + bf.y);
    }
    #pragma unroll
    for (int s = 0; s <= 5; ++s) {
      const int L = 1 << s;
      const int m2 = (lane & (L - 1)) << (7 - s);
      const float wc = Rc[m2], wsn = Rs[m2];
      const bool hi = (lane & L) != 0;
      const float br0 = __shfl_xor(gr0, L), bi0 = __shfl_xor(gi0, L);
      const float br1 = __shfl_xor(gr1, L), bi1 = __shfl_xor(gi1, L);
      const float q0ri = hi ? gr0 : br0, q0ii = hi ? gi0 : bi0;
      const float q1ri = hi ? gr1 : br1, q1ii = hi ? gi1 : bi1;
      const float q0r = fmaf(q0ri, wc, -q0ii * wsn);
      const float q0i = fmaf(q0ii, wc,  q0ri * wsn);
      const float q1r = fmaf(q1ri, wc, -q1ii * wsn);
      const float q1i = fmaf(q1ii, wc,  q1ri * wsn);
      const float p0r = hi ? br0 : gr0, p0i = hi ? bi0 : gi0;
      const float p1r = hi ? br1 : gr1, p1i = hi ? bi1 : gi1;
      gr0 = hi ? (p0r - q0r) : (p0r + q0r);
      gi0 = hi ? (p0i - q0i) : (p0i + q0i);
      gr1 = hi ? (p1r - q1r) : (p1r + q1r);
      gi1 = hi ? (p1i - q1i) : (p1i + q1i);
    }
    {
      const float wc = Rc[2 * lane], wsn = Rs[2 * lane];
      const float qr = fmaf(gr1, wc, -gi1 * wsn);
      const float qi = fmaf(gi1, wc,  gr1 * wsn);
      gr1 = gr0 - qr; gi1 = gi0 - qi;
      gr0 = gr0 + qr; gi0 = gi0 + qi;
    }
    TR[fi][i0] = gr0; TI[fi][i0] = gi0;
    TR[fi][i1] = gr1; TI[fi][i1] = gi1;
  }
  __syncthreads();

  // phase E
  const int c = tid & 127;
  const int q = tid >> 7;
  constexpr int BR4[16] = {0, 8, 4, 12, 2, 10, 6, 14, 1, 9, 5, 13, 3, 11, 7, 15};
  const float inv = 1.0f / 32768.0f;
  float* og = out + ((size_t)(b * 256 + h)) * 32768;

  #pragma unroll 1
  for (int it = 0; it < 2; ++it) {
    const int w0 = q + it * 8;
    float Ur[16], Ui[16];
    #pragma unroll
    for (int g = 0; g < 16; ++g) {
      const int gb = BR4[g];
      const float t1r = TR[gb + 16][c], t1i = TI[gb + 16][c];
      const float t0r = TR[gb][c],      t0i = TI[gb][c];
      const int iw1 = (gb * w0) & 255;
      const int iw2 = ((gb - 16) * w0) & 255;
      const float c1 = Rc[iw1], s1 = Rs[iw1];
      const float c2 = Rc[iw2], s2 = Rs[iw2];
      Ur[g] = t1r * c1 - t1i * s1 + t0r * c2 - t0i * s2;
      Ui[g] = t1r * s1 + t1i * c1 + t0r * s2 + t0i * c2;
    }
    fft16_pos(Ur, Ui);
    #pragma unroll
    for (int w1 = 0; w1 < 16; ++w1)
      og[(w1 * 16 + w0) * 128 + c] = Ur[w1] * inv;
  }
}

extern "C" void kernel_launch(void* const* d_in, const int* in_sizes, int n_in,
                              void* d_out, int out_size, void* d_ws, size_t ws_size,
                              hipStream_t stream) {
  const float* x = (const float*)d_in[0];
  const float* w = (const float*)d_in[1];
  const float* b = (const float*)d_in[2];
  float* out = (float*)d_out;
  float2* wsW = (float2*)d_ws;
  float2* wsB = wsW + 32 * 32 * 65;   // 66560 float2 each (532,480 B)

  hipLaunchKernelGGL(k0_wft_and_fill, dim3(64 + NF0), dim3(TPK), 0, stream,
                     w, b, wsW, wsB, out);
  hipLaunchKernelGGL(fourier_active, dim3(256 + NF2), dim3(TPA), 0, stream,
                     x, wsW, wsB, out);
}

// Round 19
// 68.811 us; speedup vs baseline: 5.8289x; 1.1400x over previous
//
#include <hip/hip_runtime.h>

#define TPK 512    // K0 (wft + fills) block size
#define TPA 1024   // K2 (active) block size
#define NF0 512    // fill slabs done by K0
#define FPB 5      // fill slabs embedded per active block (256*5=1280; 512+1280=1792)
#define NST (FPB * 8)   // 40 f4v stores per thread

typedef float f4v __attribute__((ext_vector_type(4)));

// bit-reverse 7 bits
__device__ __forceinline__ int br7(int k) {
  return (int)(__brev((unsigned int)k) >> 25);
}

// Barrier that waits LDS ops ONLY (single opaque asm block so the compiler's
// waitcnt pass cannot insert vmcnt(0) before s_barrier). Fill stores stay in
// flight across it.
__device__ __forceinline__ void bar_lds() {
  asm volatile("s_waitcnt lgkmcnt(0)\ns_barrier" ::: "memory");
}

// Paced fill: 3 NT stores at pacing point PT (PT = 0..14, 45 slots >= NST).
#define FILL3(PT)                                                           \
  {                                                                         \
    _Pragma("unroll")                                                       \
    for (int _j = 0; _j < 3; ++_j) {                                        \
      const int _idx = 3 * (PT) + _j;                                       \
      if (_idx < NST) {                                                     \
        const int _zi = NF0 + bid * FPB + (_idx >> 3);                      \
        const int _zb = _zi / 224;                                          \
        const int _zh = 16 + (_zi - _zb * 224);                             \
        f4v* _o4 = (f4v*)(out + ((size_t)(_zb * 256 + _zh)) * 32768);       \
        __builtin_nontemporal_store(z, &_o4[tid + ((_idx & 7) << 10)]);     \
      }                                                                     \
    }                                                                       \
  }

template <int NT>
__device__ __forceinline__ void zero_fill_slab(float* __restrict__ out,
                                               int zi, int tid) {
  const int zb = zi / 224;
  const int zh = 16 + (zi - zb * 224);
  f4v* o4 = (f4v*)(out + ((size_t)(zb * 256 + zh)) * 32768);
  const f4v z = {0.f, 0.f, 0.f, 0.f};
  #pragma unroll 4
  for (int i = tid; i < 8192; i += NT)
    __builtin_nontemporal_store(z, &o4[i]);
}

// 16-point in-register radix-2 DIT FFT, sign +. Input bit-reversed, output natural.
__device__ __forceinline__ void fft16_pos(float* ar, float* ai) {
  constexpr float TC[4][8] = {
    {1.f, 0.f, 0.f, 0.f, 0.f, 0.f, 0.f, 0.f},
    {1.f, 0.f, 0.f, 0.f, 0.f, 0.f, 0.f, 0.f},
    {1.f, 0.70710678f, 0.f, -0.70710678f, 0.f, 0.f, 0.f, 0.f},
    {1.f, 0.92387953f, 0.70710678f, 0.38268343f, 0.f, -0.38268343f, -0.70710678f, -0.92387953f}
  };
  constexpr float TS[4][8] = {
    {0.f, 0.f, 0.f, 0.f, 0.f, 0.f, 0.f, 0.f},
    {0.f, 1.f, 0.f, 0.f, 0.f, 0.f, 0.f, 0.f},
    {0.f, 0.70710678f, 1.f, 0.70710678f, 0.f, 0.f, 0.f, 0.f},
    {0.f, 0.38268343f, 0.70710678f, 0.92387953f, 1.f, 0.92387953f, 0.70710678f, 0.38268343f}
  };
  #pragma unroll
  for (int s = 0; s < 4; ++s) {
    const int L = 1 << s;
    #pragma unroll
    for (int jj = 0; jj < 8; ++jj) {
      if (jj < L) {
        const float tc = TC[s][jj], ts = TS[s][jj];
        #pragma unroll
        for (int i0 = jj; i0 < 16; i0 += 2 * L) {
          const float xr = ar[i0 + L], xi = ai[i0 + L];
          const float pr = xr * tc - xi * ts;
          const float pi = xr * ts + xi * tc;
          const float qr = ar[i0], qi = ai[i0];
          ar[i0 + L] = qr - pr; ai[i0 + L] = qi - pi;
          ar[i0]     = qr + pr; ai[i0]     = qi + pi;
        }
      }
    }
  }
}

// Phase A: W-direction partial DFT + cross-group reduction.
// DFT-16 now uses real-input even/odd decimation: 160 fma vs 288 per w0
// (E[j]=xv[j]+xv[j+8] feeds even bins; O[j]=xv[j]-xv[j+8] feeds odd bins).
template <int TPBv>
__device__ void phaseA_reduce(const float* __restrict__ src,
                              float (*XR)[128], float (*XI)[128],
                              float (*SR)[128], float (*SI)[128],
                              const float* Rc, const float* Rs, int tid) {
  constexpr int NQ = TPBv / 128;
  constexpr int JN = 16 / NQ;
  const int c = tid & 127;
  const int q = tid >> 7;

  constexpr float C16[16] = {1.f, 0.92387953f, 0.70710678f, 0.38268343f, 0.f,
                             -0.38268343f, -0.70710678f, -0.92387953f, -1.f,
                             -0.92387953f, -0.70710678f, -0.38268343f, 0.f,
                             0.38268343f, 0.70710678f, 0.92387953f};
  constexpr float S16[16] = {0.f, 0.38268343f, 0.70710678f, 0.92387953f, 1.f,
                             0.92387953f, 0.70710678f, 0.38268343f, 0.f,
                             -0.38268343f, -0.70710678f, -0.92387953f, -1.f,
                             -0.92387953f, -0.70710678f, -0.38268343f};

  float accR[17], accI[17];
  #pragma unroll
  for (int f = 0; f < 17; ++f) { accR[f] = 0.f; accI[f] = 0.f; }

  #pragma unroll
  for (int j = 0; j < JN; ++j) {
    const int w0 = q * JN + j;
    float xv[16];
    #pragma unroll
    for (int w1 = 0; w1 < 16; ++w1)
      xv[w1] = src[(w1 * 16 + w0) * 128 + c];

    // even/odd decimation of the real DFT-16
    float Ev[8], Ov[8];
    #pragma unroll
    for (int j2 = 0; j2 < 8; ++j2) {
      Ev[j2] = xv[j2] + xv[j2 + 8];
      Ov[j2] = xv[j2] - xv[j2 + 8];
    }
    float SRe[9], SIm[9];
    #pragma unroll
    for (int m = 0; m <= 4; ++m) {          // even bins g = 2m
      float sr = 0.f, si = 0.f;
      #pragma unroll
      for (int j2 = 0; j2 < 8; ++j2) {
        const int idx = (2 * m * j2) & 15;
        sr = fmaf(Ev[j2], C16[idx], sr);
        si = fmaf(Ev[j2], -S16[idx], si);
      }
      SRe[2 * m] = sr; SIm[2 * m] = si;
    }
    #pragma unroll
    for (int m = 0; m < 4; ++m) {           // odd bins g = 2m+1
      const int g = 2 * m + 1;
      float sr = 0.f, si = 0.f;
      #pragma unroll
      for (int j2 = 0; j2 < 8; ++j2) {
        const int idx = (g * j2) & 15;
        sr = fmaf(Ov[j2], C16[idx], sr);
        si = fmaf(Ov[j2], -S16[idx], si);
      }
      SRe[g] = sr; SIm[g] = si;
    }

    #pragma unroll
    for (int f = 0; f < 17; ++f) {
      const int g = f & 15;
      const float sr = (g <= 8) ? SRe[g] : SRe[16 - g];
      const float si = (g <= 8) ? SIm[g] : -SIm[16 - g];
      const int idx = (f * w0) & 255;
      const float tc = Rc[idx], ts = -Rs[idx];
      accR[f] = fmaf(sr, tc, fmaf(-si, ts, accR[f]));
      accI[f] = fmaf(sr, ts, fmaf(si, tc, accI[f]));
    }
  }
  #pragma unroll
  for (int r = 0; r < NQ / 2; ++r) {
    if (q == 2 * r) {
      if (r == 0) {
        #pragma unroll
        for (int f = 0; f < 17; ++f) { XR[f][c] = accR[f]; XI[f][c] = accI[f]; }
      } else {
        #pragma unroll
        for (int f = 0; f < 17; ++f) { XR[f][c] += accR[f]; XI[f][c] += accI[f]; }
      }
    } else if (q == 2 * r + 1) {
      if (r == 0) {
        #pragma unroll
        for (int f = 0; f < 17; ++f) { SR[f][c] = accR[f]; SI[f][c] = accI[f]; }
      } else {
        #pragma unroll
        for (int f = 0; f < 17; ++f) { SR[f][c] += accR[f]; SI[f][c] += accI[f]; }
      }
    }
    __syncthreads();
  }
  for (int u = tid; u < 17 * 128; u += TPBv) {
    const int row = u >> 7, cc = u & 127;
    XR[row][cc] += SR[row][cc];
    XI[row][cc] += SI[row][cc];
  }
  __syncthreads();
}

// 128-pt LDS DIF FFT (sign -, natural in -> bit-reversed out), 17 rows (K0).
template <int TPBv>
__device__ void fftc17_lds(float (*XR)[128], float (*XI)[128],
                           const float* Rc, const float* Rs, int tid) {
  for (int s = 6; s >= 0; --s) {
    const int L = 1 << s;
    for (int u = tid; u < 17 * 64; u += TPBv) {
      const int row = u >> 6, qq = u & 63;
      const int jj = qq & (L - 1);
      const int pos = ((qq >> s) << (s + 1)) | jj;
      const int ti = jj << (7 - s);
      const float tc = Rc[ti], ts = Rs[ti];
      const float a0r = XR[row][pos],     a0i = XI[row][pos];
      const float b0r = XR[row][pos + L], b0i = XI[row][pos + L];
      XR[row][pos] = a0r + b0r; XI[row][pos] = a0i + b0i;
      const float dr = a0r - b0r, di = a0i - b0i;
      XR[row][pos + L] = fmaf(dr, tc, di * ts);
      XI[row][pos + L] = fmaf(di, tc, -dr * ts);
    }
    __syncthreads();
  }
}

// K0: blocks 0..63 precompute w_ft/b_ft spectra; blocks 64.. zero-fill the
// first NF0 inactive output slabs (hides the wft latency chain).
__global__ __launch_bounds__(TPK) void k0_wft_and_fill(
    const float* __restrict__ wp, const float* __restrict__ bp,
    float2* __restrict__ wsW, float2* __restrict__ wsB,
    float* __restrict__ out) {
  const int bid = blockIdx.x;
  const int tid = threadIdx.x;
  if (bid >= 64) {
    zero_fill_slab<TPK>(out, bid - 64, tid);
    return;
  }
  __shared__ float XR[17][128], XI[17][128];
  __shared__ float SR[17][128], SI[17][128];
  __shared__ float Rc[256], Rs[256];
  for (int i = tid; i < 256; i += TPK) {
    float sv, cv; sincosf(6.283185307179586f * (float)i / 256.0f, &sv, &cv);
    Rc[i] = cv; Rs[i] = sv;
  }
  __syncthreads();
  const int which = bid >> 5;   // 0 = w, 1 = b
  const int ha = bid & 31;
  const int h = (ha < 16) ? ha : (224 + ha);
  const float* src = (which ? bp : wp) + (size_t)h * 32768;
  phaseA_reduce<TPK>(src, XR, XI, SR, SI, Rc, Rs, tid);
  fftc17_lds<TPK>(XR, XI, Rc, Rs, tid);
  float2* dst = which ? wsB : wsW;
  for (int u = tid; u < 32 * 65; u += TPK) {
    const int fi = u / 65, k = u - fi * 65;
    const int f = fi - 16;
    float xr, xi;
    if (f >= 0) { const int p = br7(k); xr = XR[f][p]; xi = XI[f][p]; }
    else { const int kk = (128 - k) & 127; const int p = br7(kk);
           xr = XR[-f][p]; xi = -XI[-f][p]; }
    dst[(ha * 32 + fi) * 65 + k] = make_float2(xr, xi);
  }
}

// K2: 256 active slabs (1024 thr) with FPB embedded fill slabs each,
// paced 3-stores-per-barrier-point (R13 structure, best known).
__global__ __launch_bounds__(TPA, 4) void fourier_active(
    const float* __restrict__ x, const float2* __restrict__ wsW,
    const float2* __restrict__ wsB, float* __restrict__ out) {
  const int bid = blockIdx.x;
  const int tid = threadIdx.x;
  __shared__ float XR[17][128], XI[17][128];
  __shared__ float TR[32][128], TI[32][128];
  __shared__ float Rc[256], Rs[256];
  for (int i = tid; i < 256; i += TPA) {
    float sv, cv; sincosf(6.283185307179586f * (float)i / 256.0f, &sv, &cv);
    Rc[i] = cv; Rs[i] = sv;
  }
  __syncthreads();

  const int b = bid >> 5;
  const int ha = bid & 31;
  const int h = (ha < 16) ? ha : (224 + ha);
  const float* src = x + ((size_t)(b * 256 + h)) * 32768;
  phaseA_reduce<TPA>(src, XR, XI, (float(*)[128])TR, (float(*)[128])TI,
                     Rc, Rs, tid);

  // ---- prefetch phase-C ws operands (issued BEFORE fill stores) ----
  float wfx[4], wfy[4], bfx[4], bfy[4];
  #pragma unroll
  for (int t = 0; t < 4; ++t) {
    const int u = tid + t * TPA;
    const int fi = u >> 7, k = u & 127;
    if (k <= 64) {
      const float2 wf = wsW[(ha * 32 + fi) * 65 + k];
      const float2 bf = wsB[(ha * 32 + fi) * 65 + k];
      wfx[t] = wf.x; wfy[t] = wf.y; bfx[t] = bf.x; bfy[t] = bf.y;
    } else { wfx[t] = 0.f; wfy[t] = 0.f; bfx[t] = 0.f; bfy[t] = 0.f; }
  }
  __builtin_amdgcn_sched_barrier(0);   // pin: ws loads before fill stores

  const f4v z = {0.f, 0.f, 0.f, 0.f};

  // fwd 128-pt DIF FFT (sign -) on XR/XI rows 0..16; fills paced per stage.
  #pragma unroll
  for (int s = 6; s >= 0; --s) {
    const int L = 1 << s;
    for (int u = tid; u < 17 * 64; u += TPA) {
      const int row = u >> 6, qq = u & 63;
      const int jj = qq & (L - 1);
      const int pos = ((qq >> s) << (s + 1)) | jj;
      const int ti = jj << (7 - s);
      const float tc = Rc[ti], ts = Rs[ti];
      const float a0r = XR[row][pos],     a0i = XI[row][pos];
      const float b0r = XR[row][pos + L], b0i = XI[row][pos + L];
      XR[row][pos] = a0r + b0r; XI[row][pos] = a0i + b0i;
      const float dr = a0r - b0r, di = a0i - b0i;
      XR[row][pos + L] = fmaf(dr, tc, di * ts);
      XI[row][pos + L] = fmaf(di, tc, -dr * ts);
    }
    FILL3(6 - s);            // pacing points 0..6
    bar_lds();
  }

  // phase C: pointwise from prefetched regs; write TR/TI bit-reversed.
  #pragma unroll
  for (int t = 0; t < 4; ++t) {
    const int u = tid + t * TPA;
    const int fi = u >> 7, k = u & 127;
    float gr = 0.f, gi = 0.f;
    if (k <= 64) {
      const int f = fi - 16;
      float xr, xi;
      if (f >= 0) { const int p = br7(k); xr = XR[f][p]; xi = XI[f][p]; }
      else { const int kk = (128 - k) & 127; const int p = br7(kk);
             xr = XR[-f][p]; xi = -XI[-f][p]; }
      gr = xr * wfx[t] - xi * wfy[t] + bfx[t];
      gi = xr * wfy[t] + xi * wfx[t] + bfy[t];
      const float al = (k == 0 || k == 64) ? 1.f : 2.f;
      gr *= al; gi *= al;
    }
    const int p = br7(k);
    TR[fi][p] = gr; TI[fi][p] = gi;
  }
  FILL3(7);                  // pacing point 7
  bar_lds();

  // phase D: inverse 128-pt DIT (sign +), 32 rows; fills paced per stage.
  #pragma unroll
  for (int s = 0; s <= 6; ++s) {
    const int L = 1 << s;
    for (int u = tid; u < 32 * 64; u += TPA) {
      const int row = u >> 6, qq = u & 63;
      const int jj = qq & (L - 1);
      const int pos = ((qq >> s) << (s + 1)) | jj;
      const int ti = jj << (7 - s);
      const float tc = Rc[ti], ts = Rs[ti];
      const float b0r = TR[row][pos + L], b0i = TI[row][pos + L];
      const float pr = b0r * tc - b0i * ts;
      const float pi = fmaf(b0r, ts, b0i * tc);
      const float a0r = TR[row][pos], a0i = TI[row][pos];
      TR[row][pos + L] = a0r - pr; TI[row][pos + L] = a0i - pi;
      TR[row][pos]     = a0r + pr; TI[row][pos]     = a0i + pi;
    }
    FILL3(8 + s);            // pacing points 8..14
    bar_lds();
  }

  // phase E: out[16*w1+w0, c] = (1/32768) * Re( sum_g U[g] e^{+2pi i g w1/16} )
  const int c = tid & 127;
  const int q = tid >> 7;          // 0..7
  constexpr int BR4[16] = {0, 8, 4, 12, 2, 10, 6, 14, 1, 9, 5, 13, 3, 11, 7, 15};
  const float inv = 1.0f / 32768.0f;
  float* og = out + ((size_t)(b * 256 + h)) * 32768;

  #pragma unroll 1
  for (int it = 0; it < 2; ++it) {
    const int w0 = q + it * 8;     // wave-uniform
    float Ur[16], Ui[16];
    #pragma unroll
    for (int g = 0; g < 16; ++g) {
      const int gb = BR4[g];
      const float t1r = TR[gb + 16][c], t1i = TI[gb + 16][c];
      const float t0r = TR[gb][c],      t0i = TI[gb][c];
      const int iw1 = (gb * w0) & 255;
      const int iw2 = ((gb - 16) * w0) & 255;
      const float c1 = Rc[iw1], s1 = Rs[iw1];
      const float c2 = Rc[iw2], s2 = Rs[iw2];
      Ur[g] = t1r * c1 - t1i * s1 + t0r * c2 - t0i * s2;
      Ui[g] = t1r * s1 + t1i * c1 + t0r * s2 + t0i * c2;
    }
    fft16_pos(Ur, Ui);
    #pragma unroll
    for (int w1 = 0; w1 < 16; ++w1)
      og[(w1 * 16 + w0) * 128 + c] = Ur[w1] * inv;
  }
}

extern "C" void kernel_launch(void* const* d_in, const int* in_sizes, int n_in,
                              void* d_out, int out_size, void* d_ws, size_t ws_size,
                              hipStream_t stream) {
  const float* x = (const float*)d_in[0];
  const float* w = (const float*)d_in[1];
  const float* b = (const float*)d_in[2];
  float* out = (float*)d_out;
  float2* wsW = (float2*)d_ws;
  float2* wsB = wsW + 32 * 32 * 65;   // 66560 float2 each (532,480 B)

  hipLaunchKernelGGL(k0_wft_and_fill, dim3(64 + NF0), dim3(TPK), 0, stream,
                     w, b, wsW, wsB, out);
  hipLaunchKernelGGL(fourier_active, dim3(256), dim3(TPA), 0, stream,
                     x, wsW, wsB, out);
}